// Round 5
// baseline (123.801 us; speedup 1.0000x reference)
//
#include <hip/hip_runtime.h>

#define N_ROWS 8192
#define D_IN   4096
#define D_F    8192

// Radix-4 Hadamard butterfly over two index bits.
__device__ __forceinline__ void h4(float& a, float& b, float& c, float& d) {
  float t0 = a + b, t1 = a - b, t2 = c + d, t3 = c - d;
  a = t0 + t2; c = t0 - t2;
  b = t1 + t3; d = t1 - t3;
}

// DPP move: result lane gets source lane per CTRL (quad_perm / row ops).
template<int CTRL>
__device__ __forceinline__ float dppf(float v) {
  int iv = __builtin_bit_cast(int, v);
  int r = __builtin_amdgcn_update_dpp(0, iv, CTRL, 0xF, 0xF, true);
  return __builtin_bit_cast(float, r);
}

#define DPP_QUAD_XOR1       0xB1   // quad_perm(1,0,3,2)
#define DPP_QUAD_XOR2       0x4E   // quad_perm(2,3,0,1)
#define DPP_QUAD_XOR3       0x1B   // quad_perm(3,2,1,0)
#define DPP_ROW_HALF_MIRROR 0x141  // XOR 7 within 16-lane row
#define DPP_ROW_ROR8        0x128  // rotate 8 within row == XOR 8

// One block = one row (4096 elements, 12 index bits).
// elem e = c*1024 + t*4 + i:  i=e[1:0], lane=e[7:2], wv=e[9:8], c=e[11:10]
//  - bits {0,1},{10,11}: register h4 (from global load)
//  - bits {2..7}: VALU cross-lane (DPP / permlane swaps) — zero LDS
//  - bits {8,9}: one b128 LDS RMW trip, conflict-free
// Double-buffered zbuf + fully unrolled degree pipeline: every barrier
// region mixes LDS/VALU/VMEM work (trip ∥ compute_v(next),
// gather ∥ stage(next)). 7 barriers/block (was 9), no single-pipe region.
__global__ __launch_bounds__(256, 4) void srht_kernel(
    const float* __restrict__ x,
    const float* __restrict__ rad,
    const int* __restrict__ perm,
    float* __restrict__ out)
{
  __shared__ __align__(16) float zA[D_IN];   // 16 KiB
  __shared__ __align__(16) float zB[D_IN];   // 16 KiB
  const int t    = threadIdx.x;
  const int lane = t & 63;
  const int wv   = t >> 6;
  const int row  = blockIdx.x;

  const float sg0 = (lane & 1)  ? -1.f : 1.f;
  const float sg1 = (lane & 2)  ? -1.f : 1.f;
  const float sg2 = (lane & 4)  ? -1.f : 1.f;
  const float sg3 = (lane & 8)  ? -1.f : 1.f;
  const float sg4 = (lane & 16) ? -1.f : 1.f;
  const float sg5 = (lane & 32) ? -1.f : 1.f;

  // Load x row once (coalesced float4): elem e = c*1024 + t*4 + i
  float xr[4][4];
  const float4* xrow = reinterpret_cast<const float4*>(x) + (size_t)row * (D_IN / 4);
  #pragma unroll
  for (int c = 0; c < 4; ++c) {
    float4 tv = xrow[c * 256 + t];
    xr[c][0] = tv.x; xr[c][1] = tv.y; xr[c][2] = tv.z; xr[c][3] = tv.w;
  }

  const float INV = 0.01104854345603981f;  // 1/sqrt(8192)
  float acc[32];
  #pragma unroll
  for (int k = 0; k < 32; ++k) acc[k] = INV;

  float v[4][4];

  // rad multiply + register h4s + all 6 lane-bit stages (pure VALU)
  auto compute_v = [&](int d) {
    const float4* rrow = reinterpret_cast<const float4*>(rad) + d * (D_IN / 4);
    #pragma unroll
    for (int c = 0; c < 4; ++c) {
      float4 rv = rrow[c * 256 + t];
      v[c][0] = xr[c][0] * rv.x;
      v[c][1] = xr[c][1] * rv.y;
      v[c][2] = xr[c][2] * rv.z;
      v[c][3] = xr[c][3] * rv.w;
    }
    #pragma unroll
    for (int c = 0; c < 4; ++c) h4(v[c][0], v[c][1], v[c][2], v[c][3]);
    #pragma unroll
    for (int i = 0; i < 4; ++i) h4(v[0][i], v[1][i], v[2][i], v[3][i]);

    #pragma unroll
    for (int c = 0; c < 4; ++c)
      #pragma unroll
      for (int i = 0; i < 4; ++i) {     // XOR 1 (e-bit 2)
        float p = dppf<DPP_QUAD_XOR1>(v[c][i]);
        v[c][i] = fmaf(sg0, v[c][i], p);
      }
    #pragma unroll
    for (int c = 0; c < 4; ++c)
      #pragma unroll
      for (int i = 0; i < 4; ++i) {     // XOR 2 (e-bit 3)
        float p = dppf<DPP_QUAD_XOR2>(v[c][i]);
        v[c][i] = fmaf(sg1, v[c][i], p);
      }
    #pragma unroll
    for (int c = 0; c < 4; ++c)
      #pragma unroll
      for (int i = 0; i < 4; ++i) {     // XOR 4 (e-bit 4): XOR7 then XOR3
        float p = dppf<DPP_QUAD_XOR3>(dppf<DPP_ROW_HALF_MIRROR>(v[c][i]));
        v[c][i] = fmaf(sg2, v[c][i], p);
      }
    #pragma unroll
    for (int c = 0; c < 4; ++c)
      #pragma unroll
      for (int i = 0; i < 4; ++i) {     // XOR 8 (e-bit 5)
        float p = dppf<DPP_ROW_ROR8>(v[c][i]);
        v[c][i] = fmaf(sg3, v[c][i], p);
      }
    #pragma unroll
    for (int c = 0; c < 4; ++c)
      #pragma unroll
      for (int i = 0; i < 4; ++i) {     // XOR 16 (e-bit 6)
#if __has_builtin(__builtin_amdgcn_permlane16_swap)
        unsigned iv = __builtin_bit_cast(unsigned, v[c][i]);
        auto r = __builtin_amdgcn_permlane16_swap(iv, iv, false, false);
        float p = __builtin_bit_cast(float, (lane & 16) ? r[0] : r[1]);
#else
        float p = __shfl_xor(v[c][i], 16, 64);
#endif
        v[c][i] = fmaf(sg4, v[c][i], p);
      }
    #pragma unroll
    for (int c = 0; c < 4; ++c)
      #pragma unroll
      for (int i = 0; i < 4; ++i) {     // XOR 32 (e-bit 7)
#if __has_builtin(__builtin_amdgcn_permlane32_swap)
        unsigned iv = __builtin_bit_cast(unsigned, v[c][i]);
        auto r = __builtin_amdgcn_permlane32_swap(iv, iv, false, false);
        float p = __builtin_bit_cast(float, (lane & 32) ? r[0] : r[1]);
#else
        float p = __shfl_xor(v[c][i], 32, 64);
#endif
        v[c][i] = fmaf(sg5, v[c][i], p);
      }
  };

  auto stage = [&](float* buf) {        // natural-layout b128, conflict-free
    float4* b4 = reinterpret_cast<float4*>(buf);
    #pragma unroll
    for (int c = 0; c < 4; ++c)
      b4[c * 256 + t] = make_float4(v[c][0], v[c][1], v[c][2], v[c][3]);
  };

  auto trip = [&](float* buf) {         // cross-wave bits {8,9}, b128 RMW
    float4* b4 = reinterpret_cast<float4*>(buf);
    float q[4][4];
    #pragma unroll
    for (int ww = 0; ww < 4; ++ww) {
      float4 tv = b4[wv * 256 + ww * 64 + lane];
      q[ww][0] = tv.x; q[ww][1] = tv.y; q[ww][2] = tv.z; q[ww][3] = tv.w;
    }
    #pragma unroll
    for (int i = 0; i < 4; ++i) h4(q[0][i], q[1][i], q[2][i], q[3][i]);
    #pragma unroll
    for (int ww = 0; ww < 4; ++ww)
      b4[wv * 256 + ww * 64 + lane] =
          make_float4(q[ww][0], q[ww][1], q[ww][2], q[ww][3]);
  };

  auto gather = [&](const float* buf, int d) {
    const int4* p4 = reinterpret_cast<const int4*>(perm) + d * (D_F / 4);
    #pragma unroll
    for (int it = 0; it < 8; ++it) {
      int4 p = p4[it * 256 + t];
      acc[it*4+0] *= buf[p.x];
      acc[it*4+1] *= buf[p.y];
      acc[it*4+2] *= buf[p.z];
      acc[it*4+3] *= buf[p.w];
    }
  };

  // ---- pipelined degree schedule (7 barriers) ----
  compute_v(0);
  stage(zA);
  __syncthreads();                 // B1: stage(A) visible
  trip(zA);
  compute_v(1);                    // VALU under trip's LDS ops
  __syncthreads();                 // B2: trip(A) visible
  gather(zA, 0);
  stage(zB);                       // LDS writes to B under A-gather
  __syncthreads();                 // B3: stage(B) visible
  trip(zB);
  compute_v(2);
  __syncthreads();                 // B4: trip(B) visible
  gather(zB, 1);
  stage(zA);                       // safe: all waves done gathering A (B3)
  __syncthreads();                 // B5: stage(A) visible
  trip(zA);
  __syncthreads();                 // B6: trip(A) visible
  gather(zA, 2);

  // ---- coalesced float4 output
  float4* o4 = reinterpret_cast<float4*>(out + (size_t)row * D_F);
  #pragma unroll
  for (int it = 0; it < 8; ++it)
    o4[it * 256 + t] =
        make_float4(acc[it*4+0], acc[it*4+1], acc[it*4+2], acc[it*4+3]);
}

extern "C" void kernel_launch(void* const* d_in, const int* in_sizes, int n_in,
                              void* d_out, int out_size, void* d_ws, size_t ws_size,
                              hipStream_t stream) {
  const float* x   = (const float*)d_in[0];
  const float* rad = (const float*)d_in[1];
  const int* perm  = (const int*)d_in[2];
  float* out       = (float*)d_out;
  srht_kernel<<<N_ROWS, 256, 0, stream>>>(x, rad, perm, out);
}